// Round 7
// baseline (363.819 us; speedup 1.0000x reference)
//
#include <hip/hip_runtime.h>
#include <hip/hip_bf16.h>
#include <cstdint>
#include <cstddef>

typedef __attribute__((ext_vector_type(8))) short short8;   // 8 x bf16 (4 VGPRs)
typedef __attribute__((ext_vector_type(4))) float f32x4;    // MFMA accumulator

#define GLL(gp, lp) __builtin_amdgcn_global_load_lds(                         \
    (const __attribute__((address_space(1))) void*)(gp),                      \
    (__attribute__((address_space(3))) void*)(lp), 16, 0, 0)

static __device__ __forceinline__ unsigned short f2bf(float f) {
    union { float f; uint32_t u; } v; v.f = f;
    uint32_t r = v.u + 0x7FFF + ((v.u >> 16) & 1);   // round-to-nearest-even
    return (unsigned short)(r >> 16);
}

// ---------------------------------------------------------------------------
// fp32 -> bf16 elementwise (vectorized float4 -> 4x bf16)
// ---------------------------------------------------------------------------
__global__ void cvt_x_kernel(const float* __restrict__ src,
                             unsigned short* __restrict__ dst, int n4) {
    int i = blockIdx.x * blockDim.x + threadIdx.x;
    if (i < n4) {
        float4 v = *reinterpret_cast<const float4*>(src + (size_t)i * 4);
        unsigned short* d = dst + (size_t)i * 4;
        d[0] = f2bf(v.x); d[1] = f2bf(v.y); d[2] = f2bf(v.z); d[3] = f2bf(v.w);
    }
}

// ---------------------------------------------------------------------------
// transpose + convert: src (K x N fp32, row-major) -> dst (N x K bf16)
// ---------------------------------------------------------------------------
__global__ void tr_cvt_kernel(const float* __restrict__ src,
                              unsigned short* __restrict__ dst, int K, int N) {
    __shared__ float tile[32][33];
    int n0 = blockIdx.x * 32, k0 = blockIdx.y * 32;
    int tx = threadIdx.x, ty = threadIdx.y;      // block (32, 8)
#pragma unroll
    for (int j = 0; j < 32; j += 8)
        tile[ty + j][tx] = src[(size_t)(k0 + ty + j) * N + n0 + tx];
    __syncthreads();
#pragma unroll
    for (int j = 0; j < 32; j += 8)
        dst[(size_t)(n0 + ty + j) * K + k0 + tx] = f2bf(tile[tx][ty + j]);
}

// ---------------------------------------------------------------------------
// 256x256 8-phase GEMM with 2-K-tile stage lead and counted vmcnt (T1-T5).
// 512 threads = 8 waves (2M x 4N); per-wave 128x64 out = 8mf x 4nf frags.
// BK=64; LDS 128 KiB: A[2 buf][2 half][128 r][64 k], B same at +32768 elems.
// Quarter-tile = 64 rows x 64 k = 1 GLL/thread. Swizzle slot = chunk^(row&7)
// via pre-swizzled global source (linear GLL dest) -- conflict-free b128.
//
// Per K-tile t (buf c = t&1), 4 phases, quadrant order
// (mh0,nh0) (mh0,nh1) (mh1,nh1) (mh1,nh0), A/B frags cached in regs:
//   ph1: ds_read A-mh0(8) + B-nh0(4)                  | MFMA acc[0..3][0..1]
//   ph2: ds_read B-nh1(4); stage Aq0,Aq2 (t+2 -> c)   | MFMA acc[0..3][2..3]
//   ph3: ds_read A-mh1(8); stage Bq0..3 (t+2)         | MFMA acc[4..7][2..3]
//   ph4: (no ds_read);     stage Aq1,Aq3 (t+2)        | MFMA acc[4..7][0..1]
// Each stage is issued >= 1 phase after its LDS region's last read.
// End of tile: s_waitcnt vmcnt(8) (t+1 landed, t+2's 8 loads in flight) --
// issue->wait distance ~5-6 phases, never drains to 0 in steady state.
// EPI: 0 = QKV split (+bias, Q*0.125*log2e, V transposed), 2 = bf16 gelu(relu)
// ---------------------------------------------------------------------------
template <int EPI>
__global__ __launch_bounds__(512, 2) void gemm256p8_kernel(
    const unsigned short* __restrict__ A, const unsigned short* __restrict__ BT,
    int M, int N, int K,
    const float* __restrict__ bias0, const float* __restrict__ bias1,
    const float* __restrict__ bias2,
    void* __restrict__ out0, void* __restrict__ out1, void* __restrict__ out2)
{
    extern __shared__ unsigned short lds[];   // 65536 elems = 128 KiB

    const int t = threadIdx.x, lane = t & 63, w = t >> 6;
    const int wm = w >> 2, wn = w & 3;

    // T1: XCD-aware bijective block swizzle (grids 192/256, both % 8 == 0)
    const int gx = gridDim.x;
    const int nwg = gx * gridDim.y;
    const int id = blockIdx.y * gx + blockIdx.x;
    const int swz = (id & 7) * (nwg >> 3) + (id >> 3);
    const int rowBase = (swz / gx) * 256;
    const int colBase = (swz % gx) * 256;

    // staging: thread t covers row srow of a quarter, chunk cg (pre-swizzled)
    const int srow = t >> 3;                           // 0..63
    const int cg = (t & 7) ^ (srow & 7);
    const unsigned short* gA = A + (size_t)(rowBase + srow) * K + cg * 8;
    const unsigned short* gB = BT + (size_t)(colBase + srow) * K + cg * 8;

    auto stageA = [&](int q, int buf, int kt) {        // quarter q: rows q*64..+63
        GLL(gA + (size_t)(q * 64) * K + kt, &lds[buf * 16384 + q * 4096 + t * 8]);
    };
    auto stageB = [&](int q, int buf, int kt) {
        GLL(gB + (size_t)(q * 64) * K + kt, &lds[32768 + buf * 16384 + q * 4096 + t * 8]);
    };

    // fragment ds_read offsets (elems, relative to matrix-buf base)
    int aoff[2][4][2], boff[2][2][2];
#pragma unroll
    for (int mh = 0; mh < 2; mh++)
#pragma unroll
        for (int mf = 0; mf < 4; mf++)
#pragma unroll
            for (int ks = 0; ks < 2; ks++) {
                int rih = mh * 64 + mf * 16 + (lane & 15);
                aoff[mh][mf][ks] = wm * 8192 + rih * 64
                                 + (((ks * 4 + (lane >> 4)) ^ (lane & 7)) << 3);
            }
#pragma unroll
    for (int nh = 0; nh < 2; nh++)
#pragma unroll
        for (int nf = 0; nf < 2; nf++)
#pragma unroll
            for (int ks = 0; ks < 2; ks++) {
                int cih = (wn & 1) * 64 + (nh * 2 + nf) * 16 + (lane & 15);
                boff[nh][nf][ks] = (wn >> 1) * 8192 + cih * 64
                                 + (((ks * 4 + (lane >> 4)) ^ (lane & 7)) << 3);
            }

    f32x4 acc[8][4];
#pragma unroll
    for (int mf = 0; mf < 8; mf++)
#pragma unroll
        for (int nf = 0; nf < 4; nf++) acc[mf][nf] = (f32x4){0.f, 0.f, 0.f, 0.f};

    const int NT = K >> 6;
    // prologue: fully stage t0 and t1 (8 loads each); t0 landed, t1 in flight
#pragma unroll
    for (int q = 0; q < 4; q++) { stageA(q, 0, 0); stageB(q, 0, 0); }
#pragma unroll
    for (int q = 0; q < 4; q++) { stageA(q, 1, 64); stageB(q, 1, 64); }
    asm volatile("s_waitcnt vmcnt(8)" ::: "memory");
    __builtin_amdgcn_sched_barrier(0);
    __builtin_amdgcn_s_barrier();

    for (int tt = 0; tt < NT; ++tt) {
        const int c = tt & 1;
        const int ab = c * 16384, bb = 32768 + c * 16384;
        const int kt2 = (tt + 2) << 6;
        const bool pf = (tt + 2 < NT);
        short8 ar[4][2], b0[2][2], b1[2][2];

        // ---- phase 1: (mh0, nh0) ----
#pragma unroll
        for (int mf = 0; mf < 4; mf++)
#pragma unroll
            for (int ks = 0; ks < 2; ks++)
                ar[mf][ks] = *(const short8*)&lds[ab + aoff[0][mf][ks]];
#pragma unroll
        for (int nf = 0; nf < 2; nf++)
#pragma unroll
            for (int ks = 0; ks < 2; ks++)
                b0[nf][ks] = *(const short8*)&lds[bb + boff[0][nf][ks]];
        __builtin_amdgcn_s_barrier();
        __builtin_amdgcn_s_setprio(1);
#pragma unroll
        for (int mf = 0; mf < 4; mf++)
#pragma unroll
            for (int nf = 0; nf < 2; nf++)
#pragma unroll
                for (int ks = 0; ks < 2; ks++)
                    acc[mf][nf] = __builtin_amdgcn_mfma_f32_16x16x32_bf16(
                        ar[mf][ks], b0[nf][ks], acc[mf][nf], 0, 0, 0);
        __builtin_amdgcn_s_setprio(0);
        __builtin_amdgcn_s_barrier();

        // ---- phase 2: (mh0, nh1); stage A-lo quarters of t+2 ----
#pragma unroll
        for (int nf = 0; nf < 2; nf++)
#pragma unroll
            for (int ks = 0; ks < 2; ks++)
                b1[nf][ks] = *(const short8*)&lds[bb + boff[1][nf][ks]];
        if (pf) { stageA(0, c, kt2); stageA(2, c, kt2); }
        __builtin_amdgcn_s_barrier();
        __builtin_amdgcn_s_setprio(1);
#pragma unroll
        for (int mf = 0; mf < 4; mf++)
#pragma unroll
            for (int nf = 0; nf < 2; nf++)
#pragma unroll
                for (int ks = 0; ks < 2; ks++)
                    acc[mf][2 + nf] = __builtin_amdgcn_mfma_f32_16x16x32_bf16(
                        ar[mf][ks], b1[nf][ks], acc[mf][2 + nf], 0, 0, 0);
        __builtin_amdgcn_s_setprio(0);
        __builtin_amdgcn_s_barrier();

        // ---- phase 3: (mh1, nh1); stage B quarters of t+2 ----
#pragma unroll
        for (int mf = 0; mf < 4; mf++)
#pragma unroll
            for (int ks = 0; ks < 2; ks++)
                ar[mf][ks] = *(const short8*)&lds[ab + aoff[1][mf][ks]];
        if (pf) { stageB(0, c, kt2); stageB(1, c, kt2);
                  stageB(2, c, kt2); stageB(3, c, kt2); }
        __builtin_amdgcn_s_barrier();
        __builtin_amdgcn_s_setprio(1);
#pragma unroll
        for (int mf = 0; mf < 4; mf++)
#pragma unroll
            for (int nf = 0; nf < 2; nf++)
#pragma unroll
                for (int ks = 0; ks < 2; ks++)
                    acc[4 + mf][2 + nf] = __builtin_amdgcn_mfma_f32_16x16x32_bf16(
                        ar[mf][ks], b1[nf][ks], acc[4 + mf][2 + nf], 0, 0, 0);
        __builtin_amdgcn_s_setprio(0);
        __builtin_amdgcn_s_barrier();

        // ---- phase 4: (mh1, nh0); stage A-hi quarters of t+2 ----
        if (pf) { stageA(1, c, kt2); stageA(3, c, kt2); }
        __builtin_amdgcn_s_barrier();
        __builtin_amdgcn_s_setprio(1);
#pragma unroll
        for (int mf = 0; mf < 4; mf++)
#pragma unroll
            for (int nf = 0; nf < 2; nf++)
#pragma unroll
                for (int ks = 0; ks < 2; ks++)
                    acc[4 + mf][nf] = __builtin_amdgcn_mfma_f32_16x16x32_bf16(
                        ar[mf][ks], b0[nf][ks], acc[4 + mf][nf], 0, 0, 0);
        __builtin_amdgcn_s_setprio(0);
        if (pf)                   { asm volatile("s_waitcnt vmcnt(8)" ::: "memory"); }
        else if (tt + 1 < NT)     { asm volatile("s_waitcnt vmcnt(0)" ::: "memory"); }
        __builtin_amdgcn_sched_barrier(0);
        __builtin_amdgcn_s_barrier();
    }

    // epilogue
#pragma unroll
    for (int mf = 0; mf < 8; mf++) {
#pragma unroll
        for (int nf = 0; nf < 4; nf++) {
            const int col = colBase + wn * 64 + nf * 16 + (lane & 15);
#pragma unroll
            for (int i = 0; i < 4; i++) {
                const int row = rowBase + wm * 128 + mf * 16 + (lane >> 4) * 4 + i;
                float v = acc[mf][nf][i];
                if (EPI == 0) {
                    const int bbk = row >> 11, s = row & 2047;
                    if (col < 1024) {
                        float q = (v + bias0[col]) * 0.18033688011112042f;
                        int h = col >> 6, d = col & 63;
                        ((unsigned short*)out0)[((size_t)(bbk * 16 + h) * 2048 + s) * 64 + d] = f2bf(q);
                    } else if (col < 2048) {
                        int cc = col - 1024;
                        float kv = v + bias1[cc];
                        int h = cc >> 6, d = cc & 63;
                        ((unsigned short*)out1)[((size_t)(bbk * 16 + h) * 2048 + s) * 64 + d] = f2bf(kv);
                    } else {
                        int cc = col - 2048;
                        float vv = v + bias2[cc];
                        int h = cc >> 6, d = cc & 63;
                        ((unsigned short*)out2)[((size_t)(bbk * 16 + h) * 64 + d) * 2048 + s] = f2bf(vv);
                    }
                } else {   // EPI == 2
                    float z = v + bias0[col];
                    if (z > 0.f) {
                        float u = 0.7978845608f * (z + 0.044715f * z * z * z);
                        float e = __builtin_amdgcn_exp2f(u * 2.8853900817779268f);
                        z = z * (1.f - 1.f / (e + 1.f));
                    } else z = 0.f;
                    ((unsigned short*)out0)[(size_t)row * N + col] = f2bf(z);
                }
            }
        }
    }
}

// ---------------------------------------------------------------------------
// 128x128 true-2-phase GEMM (kept for N=1024: O-proj, FFN-down). BK=64.
// EPI: 1 = f32 +bias, 3 = f32 +bias +residual
// ---------------------------------------------------------------------------
template <int EPI>
__global__ __launch_bounds__(256) void gemm128_kernel(
    const unsigned short* __restrict__ A, const unsigned short* __restrict__ BT,
    int M, int N, int K,
    const float* __restrict__ bias0,
    void* __restrict__ out0, const float* __restrict__ resid)
{
    __shared__ unsigned short Asm[2][128 * 64];
    __shared__ unsigned short Bsm[2][128 * 64];

    const int t = threadIdx.x;
    const int lane = t & 63, wv = t >> 6;
    const int wr = wv >> 1, wc = wv & 1;

    const int gx = gridDim.x;
    const int nwg = gx * gridDim.y;
    const int id = blockIdx.y * gx + blockIdx.x;
    const int swz = (id & 7) * (nwg >> 3) + (id >> 3);
    const int rowBase = (swz / gx) * 128;
    const int colBase = (swz % gx) * 128;

    const int r0 = t >> 3, c0 = t & 7;
    const int cg = c0 ^ (r0 & 7);
    const unsigned short* gA = A + (size_t)(rowBase + r0) * K + cg * 8;
    const unsigned short* gB = BT + (size_t)(colBase + r0) * K + cg * 8;

    auto stage = [&](int buf, int kt) {
#pragma unroll
        for (int j = 0; j < 4; j++) {
            GLL(gA + (size_t)(32 * j) * K + kt, &Asm[buf][t * 8 + 2048 * j]);
            GLL(gB + (size_t)(32 * j) * K + kt, &Bsm[buf][t * 8 + 2048 * j]);
        }
    };

    int aoff[4][2], boff[4][2];
#pragma unroll
    for (int m = 0; m < 4; m++)
#pragma unroll
        for (int ks = 0; ks < 2; ks++) {
            int rl = wr * 64 + m * 16 + (lane & 15);
            aoff[m][ks] = rl * 64 + (((ks * 4 + (lane >> 4)) ^ (rl & 7)) << 3);
            int cl = wc * 64 + m * 16 + (lane & 15);
            boff[m][ks] = cl * 64 + (((ks * 4 + (lane >> 4)) ^ (cl & 7)) << 3);
        }

    f32x4 acc[4][4];
#pragma unroll
    for (int m = 0; m < 4; m++)
#pragma unroll
        for (int n = 0; n < 4; n++) acc[m][n] = (f32x4){0.f, 0.f, 0.f, 0.f};

    stage(0, 0);
    asm volatile("s_waitcnt vmcnt(0)" ::: "memory");
    __builtin_amdgcn_s_barrier();

    const int nt = K >> 6;
    for (int tt = 0; tt < nt; ++tt) {
        const int cur = tt & 1;
        if (tt + 1 < nt) stage(cur ^ 1, (tt + 1) << 6);   // prefetch FIRST

        short8 b[4][2];
#pragma unroll
        for (int n = 0; n < 4; n++)
#pragma unroll
            for (int ks = 0; ks < 2; ks++)
                b[n][ks] = *(const short8*)&Bsm[cur][boff[n][ks]];
        __builtin_amdgcn_s_setprio(1);
#pragma unroll
        for (int m = 0; m < 4; m++) {
            short8 a0 = *(const short8*)&Asm[cur][aoff[m][0]];
            short8 a1 = *(const short8*)&Asm[cur][aoff[m][1]];
#pragma unroll
            for (int n = 0; n < 4; n++) {
                acc[m][n] = __builtin_amdgcn_mfma_f32_16x16x32_bf16(
                    a0, b[n][0], acc[m][n], 0, 0, 0);
                acc[m][n] = __builtin_amdgcn_mfma_f32_16x16x32_bf16(
                    a1, b[n][1], acc[m][n], 0, 0, 0);
            }
        }
        __builtin_amdgcn_s_setprio(0);

        asm volatile("s_waitcnt vmcnt(0)" ::: "memory");
        __builtin_amdgcn_sched_barrier(0);
        __builtin_amdgcn_s_barrier();
    }

#pragma unroll
    for (int m = 0; m < 4; m++) {
#pragma unroll
        for (int n = 0; n < 4; n++) {
            const int col = colBase + wc * 64 + n * 16 + (lane & 15);
#pragma unroll
            for (int i = 0; i < 4; i++) {
                const int row = rowBase + wr * 64 + m * 16 + (lane >> 4) * 4 + i;
                float v = acc[m][n][i];
                if (EPI == 1) {
                    ((float*)out0)[(size_t)row * N + col] = v + bias0[col];
                } else {
                    float z = v + bias0[col] + resid[(size_t)row * N + col];
                    ((float*)out0)[(size_t)row * N + col] = z;
                }
            }
        }
    }
}

// ---------------------------------------------------------------------------
// Flash attention, 2-phase double-buffered K/V staging.
// ---------------------------------------------------------------------------
__global__ __launch_bounds__(256, 4) void flash_attn_kernel(
    const unsigned short* __restrict__ Qb, const unsigned short* __restrict__ Kb,
    const unsigned short* __restrict__ VT, unsigned short* __restrict__ ctxb)
{
    __shared__ unsigned short Ksm[2][64 * 64];
    __shared__ unsigned short Vsm[2][64 * 64];
    __shared__ unsigned short Psm[4][16 * 64];

    const int bh = blockIdx.y;
    const int q0 = blockIdx.x * 64;
    const int t = threadIdx.x, lane = t & 63, wv = t >> 6;

    const unsigned short* Qg = Qb + (size_t)bh * 2048 * 64;
    const unsigned short* Kg = Kb + (size_t)bh * 2048 * 64;
    const unsigned short* Vg = VT + (size_t)bh * 64 * 2048;

    short8 qf[2];
    {
        int r = q0 + wv * 16 + (lane & 15);
        qf[0] = *(const short8*)&Qg[(size_t)r * 64 + ((lane >> 4) << 3)];
        qf[1] = *(const short8*)&Qg[(size_t)r * 64 + 32 + ((lane >> 4) << 3)];
    }

    f32x4 o[4];
#pragma unroll
    for (int n = 0; n < 4; n++) o[n] = (f32x4){0.f, 0.f, 0.f, 0.f};
    float mrun[4], lpart[4];
#pragma unroll
    for (int i = 0; i < 4; i++) { mrun[i] = -3.0e38f; lpart[i] = 0.f; }

    const int r0 = t >> 3, sl = t & 7;
    const int cg0 = sl ^ (r0 & 7);
    const int r1 = (256 + t) >> 3;
    const int cg1 = sl ^ (r1 & 7);

    auto stageKV = [&](int buf, int kt) {
        GLL(&Kg[(size_t)(kt + r0) * 64 + cg0 * 8], &Ksm[buf][t * 8]);
        GLL(&Kg[(size_t)(kt + r1) * 64 + cg1 * 8], &Ksm[buf][(256 + t) * 8]);
        GLL(&Vg[(size_t)r0 * 2048 + kt + cg0 * 8], &Vsm[buf][t * 8]);
        GLL(&Vg[(size_t)r1 * 2048 + kt + cg1 * 8], &Vsm[buf][(256 + t) * 8]);
    };

    unsigned short* P = &Psm[wv][0];

    int pwaddr[4][4];
#pragma unroll
    for (int n = 0; n < 4; n++)
#pragma unroll
        for (int i = 0; i < 4; i++) {
            int rl = (lane >> 4) * 4 + i;
            int col = n * 16 + (lane & 15);
            pwaddr[n][i] = rl * 64 + ((((col >> 3) ^ (rl & 7)) << 3) | (col & 7));
        }

    stageKV(0, 0);
    asm volatile("s_waitcnt vmcnt(0)" ::: "memory");
    __builtin_amdgcn_s_barrier();

    for (int tt = 0; tt < 32; ++tt) {
        const int cur = tt & 1;
        if (tt + 1 < 32) stageKV(cur ^ 1, (tt + 1) << 6);   // prefetch FIRST

        f32x4 s[4];
        __builtin_amdgcn_s_setprio(1);
#pragma unroll
        for (int n = 0; n < 4; n++) {
            s[n] = (f32x4){0.f, 0.f, 0.f, 0.f};
            int rl = n * 16 + (lane & 15);
#pragma unroll
            for (int kb = 0; kb < 2; kb++) {
                int slot = ((kb << 2) + (lane >> 4)) ^ (rl & 7);
                short8 kf = *(const short8*)&Ksm[cur][rl * 64 + slot * 8];
                s[n] = __builtin_amdgcn_mfma_f32_16x16x32_bf16(qf[kb], kf, s[n], 0, 0, 0);
            }
        }
        __builtin_amdgcn_s_setprio(0);

        float mx[4];
#pragma unroll
        for (int i = 0; i < 4; i++) {
            float m0 = fmaxf(fmaxf(s[0][i], s[1][i]), fmaxf(s[2][i], s[3][i]));
#pragma unroll
            for (int off = 1; off < 16; off <<= 1)
                m0 = fmaxf(m0, __shfl_xor(m0, off));
            mx[i] = m0;
        }
        bool ok = (mx[0] <= mrun[0] + 8.f) && (mx[1] <= mrun[1] + 8.f) &&
                  (mx[2] <= mrun[2] + 8.f) && (mx[3] <= mrun[3] + 8.f);
        if (!__all(ok)) {
#pragma unroll
            for (int i = 0; i < 4; i++) {
                float mnew = fmaxf(mrun[i], mx[i]);
                float sc = __builtin_amdgcn_exp2f(mrun[i] - mnew);
                mrun[i] = mnew;
                lpart[i] *= sc;
#pragma unroll
                for (int n = 0; n < 4; n++) o[n][i] *= sc;
            }
        }
#pragma unroll
        for (int n = 0; n < 4; n++)
#pragma unroll
            for (int i = 0; i < 4; i++) {
                float p = __builtin_amdgcn_exp2f(s[n][i] - mrun[i]);
                union { float f; uint32_t u; } pv; pv.f = p;
                P[pwaddr[n][i]] = (unsigned short)(pv.u >> 16);
                pv.u &= 0xffff0000u;
                lpart[i] += pv.f;
            }

        short8 pf[2];
        {
            int rl = lane & 15;
#pragma unroll
            for (int kb = 0; kb < 2; kb++) {
                int slot = ((kb << 2) + (lane >> 4)) ^ (rl & 7);
                pf[kb] = *(const short8*)&P[rl * 64 + slot * 8];
            }
        }
        __builtin_amdgcn_s_setprio(1);
#pragma unroll
        for (int n = 0; n < 4; n++) {
            int d = n * 16 + (lane & 15);
#pragma unroll
            for (int kb = 0; kb < 2; kb++) {
                int slot = ((kb << 2) + (lane >> 4)) ^ (d & 7);
                short8 vf = *(const short8*)&Vsm[cur][d * 64 + slot * 8];
                o[n] = __builtin_amdgcn_mfma_f32_16x16x32_bf16(pf[kb], vf, o[n], 0, 0, 0);
            }
        }
        __builtin_amdgcn_s_setprio(0);

        asm volatile("s_waitcnt vmcnt(0)" ::: "memory");
        __builtin_amdgcn_sched_barrier(0);
        __builtin_amdgcn_s_barrier();
    }

    float linv[4];
#pragma unroll
    for (int i = 0; i < 4; i++) {
        float li = lpart[i];
#pragma unroll
        for (int off = 1; off < 16; off <<= 1)
            li += __shfl_xor(li, off);
        linv[i] = 1.f / li;
    }
    const int bb = bh >> 4, h = bh & 15;
#pragma unroll
    for (int n = 0; n < 4; n++)
#pragma unroll
        for (int i = 0; i < 4; i++) {
            int srow = q0 + wv * 16 + (lane >> 4) * 4 + i;
            int d = n * 16 + (lane & 15);
            ctxb[((size_t)(bb * 2048 + srow)) * 1024 + h * 64 + d] =
                f2bf(o[n][i] * linv[i]);
        }
}

// ---------------------------------------------------------------------------
// LayerNorm over D=1024, block (256) per row.
// ---------------------------------------------------------------------------
__global__ __launch_bounds__(256) void ln_kernel(
    const float* __restrict__ in, const float* __restrict__ g,
    const float* __restrict__ bta, float* __restrict__ outf,
    unsigned short* __restrict__ outb, int mode)
{
    const int row = blockIdx.x;
    const int t = threadIdx.x, lane = t & 63, wv = t >> 6;
    const float* x = in + (size_t)row * 1024;

    float4 xv = *reinterpret_cast<const float4*>(x + t * 4);
    float s = xv.x + xv.y + xv.z + xv.w;
    float ss = xv.x * xv.x + xv.y * xv.y + xv.z * xv.z + xv.w * xv.w;
#pragma unroll
    for (int off = 1; off < 64; off <<= 1) {
        s += __shfl_xor(s, off);
        ss += __shfl_xor(ss, off);
    }
    __shared__ float red[8];
    if (lane == 0) { red[wv] = s; red[4 + wv] = ss; }
    __syncthreads();
    s = red[0] + red[1] + red[2] + red[3];
    ss = red[4] + red[5] + red[6] + red[7];
    const float mu = s * (1.f / 1024.f);
    const float var = ss * (1.f / 1024.f) - mu * mu;
    const float inv = rsqrtf(var + 1e-12f);

    float4 gv = *reinterpret_cast<const float4*>(g + t * 4);
    float4 bv = *reinterpret_cast<const float4*>(bta + t * 4);
    float o0 = (xv.x - mu) * inv * gv.x + bv.x;
    float o1 = (xv.y - mu) * inv * gv.y + bv.y;
    float o2 = (xv.z - mu) * inv * gv.z + bv.z;
    float o3 = (xv.w - mu) * inv * gv.w + bv.w;

    float4* of = reinterpret_cast<float4*>(outf + (size_t)row * 1024 + t * 4);
    *of = (float4){o0, o1, o2, o3};
    if (mode == 0) {
        unsigned short* ob = outb + (size_t)row * 1024 + t * 4;
        ob[0] = f2bf(o0); ob[1] = f2bf(o1); ob[2] = f2bf(o2); ob[3] = f2bf(o3);
    }
}

// ---------------------------------------------------------------------------
extern "C" void kernel_launch(void* const* d_in, const int* in_sizes, int n_in,
                              void* d_out, int out_size, void* d_ws, size_t ws_size,
                              hipStream_t stream) {
    const float* x     = (const float*)d_in[0];
    const float* Wq    = (const float*)d_in[1];
    const float* bq    = (const float*)d_in[2];
    const float* Wk    = (const float*)d_in[3];
    const float* bk    = (const float*)d_in[4];
    const float* Wv    = (const float*)d_in[5];
    const float* bv    = (const float*)d_in[6];
    const float* Wo    = (const float*)d_in[7];
    const float* bo    = (const float*)d_in[8];
    const float* ln1_g = (const float*)d_in[9];
    const float* ln1_b = (const float*)d_in[10];
    const float* W1    = (const float*)d_in[11];
    const float* b1    = (const float*)d_in[12];
    const float* W2    = (const float*)d_in[13];
    const float* b2    = (const float*)d_in[14];
    const float* ln2_g = (const float*)d_in[15];
    const float* ln2_b = (const float*)d_in[16];
    float* out = (float*)d_out;

    const int B = 2, S = 2048, D = 1024, H = 16, F = 4096;
    const int M = B * S;                    // 4096 tokens

    char* w = (char*)d_ws;
    size_t off = 0;
    auto alloc = [&](size_t bytes) {
        size_t o = off; off += (bytes + 255) & ~(size_t)255; return o;
    };
    unsigned short* xb      = (unsigned short*)(w + alloc((size_t)M * D * 2));   // also ctxb
    unsigned short* WqkvT   = (unsigned short*)(w + alloc((size_t)3 * D * D * 2));
    unsigned short* WoT     = (unsigned short*)(w + alloc((size_t)D * D * 2));
    unsigned short* W1T     = (unsigned short*)(w + alloc((size_t)D * F * 2));
    unsigned short* W2T     = (unsigned short*)(w + alloc((size_t)F * D * 2));
    unsigned short* Qbuf    = (unsigned short*)(w + alloc((size_t)M * D * 2));
    unsigned short* Kbuf    = (unsigned short*)(w + alloc((size_t)M * D * 2));
    unsigned short* VTbuf   = (unsigned short*)(w + alloc((size_t)M * D * 2));
    float*          attnraw = (float*)(w + alloc((size_t)M * D * 4));            // also z
    float*          attnlnf = (float*)(w + alloc((size_t)M * D * 4));
    unsigned short* attnlnb = (unsigned short*)(w + alloc((size_t)M * D * 2));
    unsigned short* hbuf    = (unsigned short*)(w + alloc((size_t)M * F * 2));
    unsigned short* ctxb    = xb;   // reuse (xb consumed by GEMM1 before attn)

    hipFuncSetAttribute((const void*)gemm256p8_kernel<0>,
                        hipFuncAttributeMaxDynamicSharedMemorySize, 131072);
    hipFuncSetAttribute((const void*)gemm256p8_kernel<2>,
                        hipFuncAttributeMaxDynamicSharedMemorySize, 131072);

    // 1) conversions / transposes
    cvt_x_kernel<<<(M * D / 4 + 255) / 256, 256, 0, stream>>>(x, xb, M * D / 4);
    dim3 tb(32, 8);
    tr_cvt_kernel<<<dim3(D / 32, D / 32), tb, 0, stream>>>(Wq, WqkvT,             D, D);
    tr_cvt_kernel<<<dim3(D / 32, D / 32), tb, 0, stream>>>(Wk, WqkvT + D * D,     D, D);
    tr_cvt_kernel<<<dim3(D / 32, D / 32), tb, 0, stream>>>(Wv, WqkvT + 2 * D * D, D, D);
    tr_cvt_kernel<<<dim3(D / 32, D / 32), tb, 0, stream>>>(Wo, WoT,               D, D);
    tr_cvt_kernel<<<dim3(F / 32, D / 32), tb, 0, stream>>>(W1, W1T,               D, F);
    tr_cvt_kernel<<<dim3(D / 32, F / 32), tb, 0, stream>>>(W2, W2T,               F, D);

    // 2) fused QKV projection (256-tile 8-phase)
    gemm256p8_kernel<0><<<dim3(3 * D / 256, M / 256), 512, 131072, stream>>>(
        xb, WqkvT, M, 3 * D, D, bq, bk, bv, Qbuf, Kbuf, VTbuf);

    // 3) flash attention -> ctx bf16 (token-major)
    flash_attn_kernel<<<dim3(S / 64, B * H), 256, 0, stream>>>(
        Qbuf, Kbuf, VTbuf, ctxb);

    // 4) output projection -> fp32 (128-tile 2-phase; N=1024)
    gemm128_kernel<1><<<dim3(D / 128, M / 128), 256, 0, stream>>>(
        ctxb, WoT, M, D, D, bo, attnraw, nullptr);

    // 5) LN1 -> fp32 residual copy + bf16 GEMM input
    ln_kernel<<<M, 256, 0, stream>>>(attnraw, ln1_g, ln1_b, attnlnf, attnlnb, 0);

    // 6) FFN up + relu + tanh-gelu -> bf16 (256-tile 8-phase)
    gemm256p8_kernel<2><<<dim3(F / 256, M / 256), 512, 131072, stream>>>(
        attnlnb, W1T, M, F, D, b1, nullptr, nullptr, hbuf, nullptr, nullptr);

    // 7) FFN down + bias + residual -> fp32 (128-tile 2-phase; K=4096)
    gemm128_kernel<3><<<dim3(D / 128, M / 128), 256, 0, stream>>>(
        hbuf, W2T, M, D, F, b2, attnraw, attnlnf);

    // 8) LN2 -> final output fp32
    ln_kernel<<<M, 256, 0, stream>>>(attnraw, ln2_g, ln2_b, out, nullptr, 1);
}

// Round 8
// 335.152 us; speedup vs baseline: 1.0855x; 1.0855x over previous
//
#include <hip/hip_runtime.h>
#include <hip/hip_bf16.h>
#include <cstdint>
#include <cstddef>

typedef __attribute__((ext_vector_type(8))) short short8;   // 8 x bf16 (4 VGPRs)
typedef __attribute__((ext_vector_type(4))) float f32x4;    // MFMA accumulator

#define GLL(gp, lp) __builtin_amdgcn_global_load_lds(                         \
    (const __attribute__((address_space(1))) void*)(gp),                      \
    (__attribute__((address_space(3))) void*)(lp), 16, 0, 0)

static __device__ __forceinline__ unsigned short f2bf(float f) {
    union { float f; uint32_t u; } v; v.f = f;
    uint32_t r = v.u + 0x7FFF + ((v.u >> 16) & 1);   // round-to-nearest-even
    return (unsigned short)(r >> 16);
}

// ---------------------------------------------------------------------------
// fp32 -> bf16 elementwise (vectorized float4 -> 4x bf16)
// ---------------------------------------------------------------------------
__global__ void cvt_x_kernel(const float* __restrict__ src,
                             unsigned short* __restrict__ dst, int n4) {
    int i = blockIdx.x * blockDim.x + threadIdx.x;
    if (i < n4) {
        float4 v = *reinterpret_cast<const float4*>(src + (size_t)i * 4);
        unsigned short* d = dst + (size_t)i * 4;
        d[0] = f2bf(v.x); d[1] = f2bf(v.y); d[2] = f2bf(v.z); d[3] = f2bf(v.w);
    }
}

// ---------------------------------------------------------------------------
// transpose + convert: src (K x N fp32, row-major) -> dst (N x K bf16)
// ---------------------------------------------------------------------------
__global__ void tr_cvt_kernel(const float* __restrict__ src,
                              unsigned short* __restrict__ dst, int K, int N) {
    __shared__ float tile[32][33];
    int n0 = blockIdx.x * 32, k0 = blockIdx.y * 32;
    int tx = threadIdx.x, ty = threadIdx.y;      // block (32, 8)
#pragma unroll
    for (int j = 0; j < 32; j += 8)
        tile[ty + j][tx] = src[(size_t)(k0 + ty + j) * N + n0 + tx];
    __syncthreads();
#pragma unroll
    for (int j = 0; j < 32; j += 8)
        dst[(size_t)(n0 + ty + j) * K + k0 + tx] = f2bf(tile[tx][ty + j]);
}

// ---------------------------------------------------------------------------
// 128x128 GEMM, BK=32, TRIPLE-buffered LDS + counted vmcnt (T4):
// compute buf t while stage(t+1) is LANDED and stage(t+2) is IN FLIGHT.
// Per K-step: issue stage((t+2)%3) [4 GLL/thread]; ds_read + 16 MFMA on
// buf t%3; s_waitcnt vmcnt(4) (waits t+1 landed, t+2 stays in flight);
// ONE s_barrier. Stage lead ~1.7 steps; never drains to 0 in steady state.
// LDS 48 KiB -> 3 blocks/CU where the grid allows (QKV, FFN-up).
// Swizzle: LDS slot s of row r holds k-chunk s ^ ((r>>1)&3) via pre-swizzled
// global source (linear GLL dest); frag reads 2-way max (measured 0 confl).
// EPI: 0 = QKV split (+bias, Q*0.125*log2e, V transposed), 1 = f32 +bias,
//      2 = bf16 tanh-gelu(relu(+bias)), 3 = f32 +bias +residual
// ---------------------------------------------------------------------------
template <int EPI>
__global__ __launch_bounds__(256) void gemm128_kernel(
    const unsigned short* __restrict__ A, const unsigned short* __restrict__ BT,
    int M, int N, int K,
    const float* __restrict__ bias0, const float* __restrict__ bias1,
    const float* __restrict__ bias2,
    void* __restrict__ out0, void* __restrict__ out1, void* __restrict__ out2,
    const float* __restrict__ resid)
{
    __shared__ unsigned short Asm[3][128 * 32];
    __shared__ unsigned short Bsm[3][128 * 32];

    const int t = threadIdx.x;
    const int lane = t & 63, wv = t >> 6;
    const int wr = wv >> 1, wc = wv & 1;

    // T1: XCD-aware bijective block swizzle (all grids % 8 == 0)
    const int gx = gridDim.x;
    const int nwg = gx * gridDim.y;
    const int id = blockIdx.y * gx + blockIdx.x;
    const int swz = (id & 7) * (nwg >> 3) + (id >> 3);
    const int rowBase = (swz / gx) * 128;
    const int colBase = (swz % gx) * 128;

    // staging: chunk idx (0..511) -> row = idx>>2, slot = idx&3;
    // slot s of row r holds global k-chunk s ^ ((r>>1)&3)
    const int r0 = t >> 2,        s0 = t & 3;
    const int cg0 = s0 ^ ((r0 >> 1) & 3);
    const int r1 = (256 + t) >> 2;
    const int cg1 = s0 ^ ((r1 >> 1) & 3);
    const unsigned short* gA0 = A + (size_t)(rowBase + r0) * K + cg0 * 8;
    const unsigned short* gA1 = A + (size_t)(rowBase + r1) * K + cg1 * 8;
    const unsigned short* gB0 = BT + (size_t)(colBase + r0) * K + cg0 * 8;
    const unsigned short* gB1 = BT + (size_t)(colBase + r1) * K + cg1 * 8;

    auto stage = [&](int buf, int kt) {    // 4 GLL per thread
        GLL(gA0 + kt, &Asm[buf][t * 8]);
        GLL(gA1 + kt, &Asm[buf][(256 + t) * 8]);
        GLL(gB0 + kt, &Bsm[buf][t * 8]);
        GLL(gB1 + kt, &Bsm[buf][(256 + t) * 8]);
    };

    // fragment read offsets (halfwords) with matching swizzle
    int aoff[4], boff[4];
#pragma unroll
    for (int m = 0; m < 4; m++) {
        int rl = wr * 64 + m * 16 + (lane & 15);
        aoff[m] = rl * 32 + (((lane >> 4) ^ ((rl >> 1) & 3)) << 3);
        int cl = wc * 64 + m * 16 + (lane & 15);
        boff[m] = cl * 32 + (((lane >> 4) ^ ((cl >> 1) & 3)) << 3);
    }

    f32x4 acc[4][4];
#pragma unroll
    for (int m = 0; m < 4; m++)
#pragma unroll
        for (int n = 0; n < 4; n++) acc[m][n] = (f32x4){0.f, 0.f, 0.f, 0.f};

    const int nt = K >> 5;                 // BK = 32; nt >= 32 always here
    // prologue: stage t0, t1 (8 loads out); wait t0 landed (t1 in flight)
    stage(0, 0);
    stage(1, 32);
    asm volatile("s_waitcnt vmcnt(4)" ::: "memory");
    __builtin_amdgcn_sched_barrier(0);
    __builtin_amdgcn_s_barrier();

    for (int tt = 0; tt < nt; ++tt) {
        const int cur = tt % 3;
        if (tt + 2 < nt) stage((tt + 2) % 3, (tt + 2) << 5);   // issue FIRST

        short8 a[4], b[4];
#pragma unroll
        for (int m = 0; m < 4; m++) a[m] = *(const short8*)&Asm[cur][aoff[m]];
#pragma unroll
        for (int n = 0; n < 4; n++) b[n] = *(const short8*)&Bsm[cur][boff[n]];
        __builtin_amdgcn_s_setprio(1);
#pragma unroll
        for (int m = 0; m < 4; m++)
#pragma unroll
            for (int n = 0; n < 4; n++)
                acc[m][n] = __builtin_amdgcn_mfma_f32_16x16x32_bf16(
                    a[m], b[n], acc[m][n], 0, 0, 0);
        __builtin_amdgcn_s_setprio(0);

        if (tt + 2 < nt) {
            asm volatile("s_waitcnt vmcnt(4)" ::: "memory");   // t+1 landed
        } else if (tt + 1 < nt) {
            asm volatile("s_waitcnt vmcnt(0)" ::: "memory");   // final drain
        }
        if (tt + 1 < nt) {
            __builtin_amdgcn_sched_barrier(0);
            __builtin_amdgcn_s_barrier();
        }
    }

    // epilogue: lane holds C[row = (lane>>4)*4+i][col = lane&15] per frag
#pragma unroll
    for (int m = 0; m < 4; m++) {
#pragma unroll
        for (int n = 0; n < 4; n++) {
            const int col = colBase + wc * 64 + n * 16 + (lane & 15);
#pragma unroll
            for (int i = 0; i < 4; i++) {
                const int row = rowBase + wr * 64 + m * 16 + (lane >> 4) * 4 + i;
                float v = acc[m][n][i];
                if (EPI == 0) {
                    const int bb = row >> 11, s = row & 2047;
                    if (col < 1024) {
                        float q = (v + bias0[col]) * 0.18033688011112042f;
                        int h = col >> 6, d = col & 63;
                        ((unsigned short*)out0)[((size_t)(bb * 16 + h) * 2048 + s) * 64 + d] = f2bf(q);
                    } else if (col < 2048) {
                        int cc = col - 1024;
                        float kv = v + bias1[cc];
                        int h = cc >> 6, d = cc & 63;
                        ((unsigned short*)out1)[((size_t)(bb * 16 + h) * 2048 + s) * 64 + d] = f2bf(kv);
                    } else {
                        int cc = col - 2048;
                        float vv = v + bias2[cc];
                        int h = cc >> 6, d = cc & 63;
                        ((unsigned short*)out2)[((size_t)(bb * 16 + h) * 64 + d) * 2048 + s] = f2bf(vv);
                    }
                } else if (EPI == 1) {
                    ((float*)out0)[(size_t)row * N + col] = v + bias0[col];
                } else if (EPI == 2) {
                    float z = v + bias0[col];
                    if (z > 0.f) {
                        float u = 0.7978845608f * (z + 0.044715f * z * z * z);
                        float e = __builtin_amdgcn_exp2f(u * 2.8853900817779268f);
                        z = z * (1.f - 1.f / (e + 1.f));
                    } else z = 0.f;
                    ((unsigned short*)out0)[(size_t)row * N + col] = f2bf(z);
                } else {
                    float z = v + bias0[col] + resid[(size_t)row * N + col];
                    ((float*)out0)[(size_t)row * N + col] = z;
                }
            }
        }
    }
}

// ---------------------------------------------------------------------------
// Flash attention, 2-phase double-buffered K/V staging (R6 config, unchanged).
// ---------------------------------------------------------------------------
__global__ __launch_bounds__(256, 4) void flash_attn_kernel(
    const unsigned short* __restrict__ Qb, const unsigned short* __restrict__ Kb,
    const unsigned short* __restrict__ VT, unsigned short* __restrict__ ctxb)
{
    __shared__ unsigned short Ksm[2][64 * 64];
    __shared__ unsigned short Vsm[2][64 * 64];
    __shared__ unsigned short Psm[4][16 * 64];

    const int bh = blockIdx.y;
    const int q0 = blockIdx.x * 64;
    const int t = threadIdx.x, lane = t & 63, wv = t >> 6;

    const unsigned short* Qg = Qb + (size_t)bh * 2048 * 64;
    const unsigned short* Kg = Kb + (size_t)bh * 2048 * 64;
    const unsigned short* Vg = VT + (size_t)bh * 64 * 2048;

    short8 qf[2];
    {
        int r = q0 + wv * 16 + (lane & 15);
        qf[0] = *(const short8*)&Qg[(size_t)r * 64 + ((lane >> 4) << 3)];
        qf[1] = *(const short8*)&Qg[(size_t)r * 64 + 32 + ((lane >> 4) << 3)];
    }

    f32x4 o[4];
#pragma unroll
    for (int n = 0; n < 4; n++) o[n] = (f32x4){0.f, 0.f, 0.f, 0.f};
    float mrun[4], lpart[4];
#pragma unroll
    for (int i = 0; i < 4; i++) { mrun[i] = -3.0e38f; lpart[i] = 0.f; }

    const int r0 = t >> 3, sl = t & 7;
    const int cg0 = sl ^ (r0 & 7);
    const int r1 = (256 + t) >> 3;
    const int cg1 = sl ^ (r1 & 7);

    auto stageKV = [&](int buf, int kt) {
        GLL(&Kg[(size_t)(kt + r0) * 64 + cg0 * 8], &Ksm[buf][t * 8]);
        GLL(&Kg[(size_t)(kt + r1) * 64 + cg1 * 8], &Ksm[buf][(256 + t) * 8]);
        GLL(&Vg[(size_t)r0 * 2048 + kt + cg0 * 8], &Vsm[buf][t * 8]);
        GLL(&Vg[(size_t)r1 * 2048 + kt + cg1 * 8], &Vsm[buf][(256 + t) * 8]);
    };

    unsigned short* P = &Psm[wv][0];

    int pwaddr[4][4];
#pragma unroll
    for (int n = 0; n < 4; n++)
#pragma unroll
        for (int i = 0; i < 4; i++) {
            int rl = (lane >> 4) * 4 + i;
            int col = n * 16 + (lane & 15);
            pwaddr[n][i] = rl * 64 + ((((col >> 3) ^ (rl & 7)) << 3) | (col & 7));
        }

    stageKV(0, 0);
    asm volatile("s_waitcnt vmcnt(0)" ::: "memory");
    __builtin_amdgcn_s_barrier();

    for (int tt = 0; tt < 32; ++tt) {
        const int cur = tt & 1;
        if (tt + 1 < 32) stageKV(cur ^ 1, (tt + 1) << 6);   // prefetch FIRST

        f32x4 s[4];
        __builtin_amdgcn_s_setprio(1);
#pragma unroll
        for (int n = 0; n < 4; n++) {
            s[n] = (f32x4){0.f, 0.f, 0.f, 0.f};
            int rl = n * 16 + (lane & 15);
#pragma unroll
            for (int kb = 0; kb < 2; kb++) {
                int slot = ((kb << 2) + (lane >> 4)) ^ (rl & 7);
                short8 kf = *(const short8*)&Ksm[cur][rl * 64 + slot * 8];
                s[n] = __builtin_amdgcn_mfma_f32_16x16x32_bf16(qf[kb], kf, s[n], 0, 0, 0);
            }
        }
        __builtin_amdgcn_s_setprio(0);

        float mx[4];
#pragma unroll
        for (int i = 0; i < 4; i++) {
            float m0 = fmaxf(fmaxf(s[0][i], s[1][i]), fmaxf(s[2][i], s[3][i]));
#pragma unroll
            for (int off = 1; off < 16; off <<= 1)
                m0 = fmaxf(m0, __shfl_xor(m0, off));
            mx[i] = m0;
        }
        bool ok = (mx[0] <= mrun[0] + 8.f) && (mx[1] <= mrun[1] + 8.f) &&
                  (mx[2] <= mrun[2] + 8.f) && (mx[3] <= mrun[3] + 8.f);
        if (!__all(ok)) {
#pragma unroll
            for (int i = 0; i < 4; i++) {
                float mnew = fmaxf(mrun[i], mx[i]);
                float sc = __builtin_amdgcn_exp2f(mrun[i] - mnew);
                mrun[i] = mnew;
                lpart[i] *= sc;
#pragma unroll
                for (int n = 0; n < 4; n++) o[n][i] *= sc;
            }
        }
#pragma unroll
        for (int n = 0; n < 4; n++)
#pragma unroll
            for (int i = 0; i < 4; i++) {
                float p = __builtin_amdgcn_exp2f(s[n][i] - mrun[i]);
                union { float f; uint32_t u; } pv; pv.f = p;
                P[pwaddr[n][i]] = (unsigned short)(pv.u >> 16);
                pv.u &= 0xffff0000u;
                lpart[i] += pv.f;
            }

        short8 pf[2];
        {
            int rl = lane & 15;
#pragma unroll
            for (int kb = 0; kb < 2; kb++) {
                int slot = ((kb << 2) + (lane >> 4)) ^ (rl & 7);
                pf[kb] = *(const short8*)&P[rl * 64 + slot * 8];
            }
        }
        __builtin_amdgcn_s_setprio(1);
#pragma unroll
        for (int n = 0; n < 4; n++) {
            int d = n * 16 + (lane & 15);
#pragma unroll
            for (int kb = 0; kb < 2; kb++) {
                int slot = ((kb << 2) + (lane >> 4)) ^ (d & 7);
                short8 vf = *(const short8*)&Vsm[cur][d * 64 + slot * 8];
                o[n] = __builtin_amdgcn_mfma_f32_16x16x32_bf16(pf[kb], vf, o[n], 0, 0, 0);
            }
        }
        __builtin_amdgcn_s_setprio(0);

        asm volatile("s_waitcnt vmcnt(0)" ::: "memory");
        __builtin_amdgcn_sched_barrier(0);
        __builtin_amdgcn_s_barrier();
    }

    float linv[4];
#pragma unroll
    for (int i = 0; i < 4; i++) {
        float li = lpart[i];
#pragma unroll
        for (int off = 1; off < 16; off <<= 1)
            li += __shfl_xor(li, off);
        linv[i] = 1.f / li;
    }
    const int bb = bh >> 4, h = bh & 15;
#pragma unroll
    for (int n = 0; n < 4; n++)
#pragma unroll
        for (int i = 0; i < 4; i++) {
            int srow = q0 + wv * 16 + (lane >> 4) * 4 + i;
            int d = n * 16 + (lane & 15);
            ctxb[((size_t)(bb * 2048 + srow)) * 1024 + h * 64 + d] =
                f2bf(o[n][i] * linv[i]);
        }
}

// ---------------------------------------------------------------------------
// LayerNorm over D=1024, block (256) per row.
// ---------------------------------------------------------------------------
__global__ __launch_bounds__(256) void ln_kernel(
    const float* __restrict__ in, const float* __restrict__ g,
    const float* __restrict__ bta, float* __restrict__ outf,
    unsigned short* __restrict__ outb, int mode)
{
    const int row = blockIdx.x;
    const int t = threadIdx.x, lane = t & 63, wv = t >> 6;
    const float* x = in + (size_t)row * 1024;

    float4 xv = *reinterpret_cast<const float4*>(x + t * 4);
    float s = xv.x + xv.y + xv.z + xv.w;
    float ss = xv.x * xv.x + xv.y * xv.y + xv.z * xv.z + xv.w * xv.w;
#pragma unroll
    for (int off = 1; off < 64; off <<= 1) {
        s += __shfl_xor(s, off);
        ss += __shfl_xor(ss, off);
    }
    __shared__ float red[8];
    if (lane == 0) { red[wv] = s; red[4 + wv] = ss; }
    __syncthreads();
    s = red[0] + red[1] + red[2] + red[3];
    ss = red[4] + red[5] + red[6] + red[7];
    const float mu = s * (1.f / 1024.f);
    const float var = ss * (1.f / 1024.f) - mu * mu;
    const float inv = rsqrtf(var + 1e-12f);

    float4 gv = *reinterpret_cast<const float4*>(g + t * 4);
    float4 bv = *reinterpret_cast<const float4*>(bta + t * 4);
    float o0 = (xv.x - mu) * inv * gv.x + bv.x;
    float o1 = (xv.y - mu) * inv * gv.y + bv.y;
    float o2 = (xv.z - mu) * inv * gv.z + bv.z;
    float o3 = (xv.w - mu) * inv * gv.w + bv.w;

    float4* of = reinterpret_cast<float4*>(outf + (size_t)row * 1024 + t * 4);
    *of = (float4){o0, o1, o2, o3};
    if (mode == 0) {
        unsigned short* ob = outb + (size_t)row * 1024 + t * 4;
        ob[0] = f2bf(o0); ob[1] = f2bf(o1); ob[2] = f2bf(o2); ob[3] = f2bf(o3);
    }
}

// ---------------------------------------------------------------------------
extern "C" void kernel_launch(void* const* d_in, const int* in_sizes, int n_in,
                              void* d_out, int out_size, void* d_ws, size_t ws_size,
                              hipStream_t stream) {
    const float* x     = (const float*)d_in[0];
    const float* Wq    = (const float*)d_in[1];
    const float* bq    = (const float*)d_in[2];
    const float* Wk    = (const float*)d_in[3];
    const float* bk    = (const float*)d_in[4];
    const float* Wv    = (const float*)d_in[5];
    const float* bv    = (const float*)d_in[6];
    const float* Wo    = (const float*)d_in[7];
    const float* bo    = (const float*)d_in[8];
    const float* ln1_g = (const float*)d_in[9];
    const float* ln1_b = (const float*)d_in[10];
    const float* W1    = (const float*)d_in[11];
    const float* b1    = (const float*)d_in[12];
    const float* W2    = (const float*)d_in[13];
    const float* b2    = (const float*)d_in[14];
    const float* ln2_g = (const float*)d_in[15];
    const float* ln2_b = (const float*)d_in[16];
    float* out = (float*)d_out;

    const int B = 2, S = 2048, D = 1024, H = 16, F = 4096;
    const int M = B * S;                    // 4096 tokens

    char* w = (char*)d_ws;
    size_t off = 0;
    auto alloc = [&](size_t bytes) {
        size_t o = off; off += (bytes + 255) & ~(size_t)255; return o;
    };
    unsigned short* xb      = (unsigned short*)(w + alloc((size_t)M * D * 2));   // also ctxb
    unsigned short* WqkvT   = (unsigned short*)(w + alloc((size_t)3 * D * D * 2));
    unsigned short* WoT     = (unsigned short*)(w + alloc((size_t)D * D * 2));
    unsigned short* W1T     = (unsigned short*)(w + alloc((size_t)D * F * 2));
    unsigned short* W2T     = (unsigned short*)(w + alloc((size_t)F * D * 2));
    unsigned short* Qbuf    = (unsigned short*)(w + alloc((size_t)M * D * 2));
    unsigned short* Kbuf    = (unsigned short*)(w + alloc((size_t)M * D * 2));
    unsigned short* VTbuf   = (unsigned short*)(w + alloc((size_t)M * D * 2));
    float*          attnraw = (float*)(w + alloc((size_t)M * D * 4));            // also z
    float*          attnlnf = (float*)(w + alloc((size_t)M * D * 4));
    unsigned short* attnlnb = (unsigned short*)(w + alloc((size_t)M * D * 2));
    unsigned short* hbuf    = (unsigned short*)(w + alloc((size_t)M * F * 2));
    unsigned short* ctxb    = xb;   // reuse (xb consumed by GEMM1 before attn)

    // 1) conversions / transposes
    cvt_x_kernel<<<(M * D / 4 + 255) / 256, 256, 0, stream>>>(x, xb, M * D / 4);
    dim3 tb(32, 8);
    tr_cvt_kernel<<<dim3(D / 32, D / 32), tb, 0, stream>>>(Wq, WqkvT,             D, D);
    tr_cvt_kernel<<<dim3(D / 32, D / 32), tb, 0, stream>>>(Wk, WqkvT + D * D,     D, D);
    tr_cvt_kernel<<<dim3(D / 32, D / 32), tb, 0, stream>>>(Wv, WqkvT + 2 * D * D, D, D);
    tr_cvt_kernel<<<dim3(D / 32, D / 32), tb, 0, stream>>>(Wo, WoT,               D, D);
    tr_cvt_kernel<<<dim3(F / 32, D / 32), tb, 0, stream>>>(W1, W1T,               D, F);
    tr_cvt_kernel<<<dim3(D / 32, F / 32), tb, 0, stream>>>(W2, W2T,               F, D);

    // 2) fused QKV projection (3-buf counted-vmcnt; grid 768 = 3/CU)
    gemm128_kernel<0><<<dim3(3 * D / 128, M / 128), 256, 0, stream>>>(
        xb, WqkvT, M, 3 * D, D, bq, bk, bv, Qbuf, Kbuf, VTbuf, nullptr);

    // 3) flash attention -> ctx bf16 (token-major)
    flash_attn_kernel<<<dim3(S / 64, B * H), 256, 0, stream>>>(
        Qbuf, Kbuf, VTbuf, ctxb);

    // 4) output projection -> fp32
    gemm128_kernel<1><<<dim3(D / 128, M / 128), 256, 0, stream>>>(
        ctxb, WoT, M, D, D, bo, nullptr, nullptr, attnraw, nullptr, nullptr, nullptr);

    // 5) LN1 -> fp32 residual copy + bf16 GEMM input
    ln_kernel<<<M, 256, 0, stream>>>(attnraw, ln1_g, ln1_b, attnlnf, attnlnb, 0);

    // 6) FFN up + relu + tanh-gelu -> bf16 (grid 1024 = 3/CU LDS-capped)
    gemm128_kernel<2><<<dim3(F / 128, M / 128), 256, 0, stream>>>(
        attnlnb, W1T, M, F, D, b1, nullptr, nullptr, hbuf, nullptr, nullptr, nullptr);

    // 7) FFN down + bias + residual -> fp32 (K=4096)
    gemm128_kernel<3><<<dim3(D / 128, M / 128), 256, 0, stream>>>(
        hbuf, W2T, M, D, F, b2, nullptr, nullptr, attnraw, nullptr, nullptr, attnlnf);

    // 8) LN2 -> final output fp32
    ln_kernel<<<M, 256, 0, stream>>>(attnraw, ln2_g, ln2_b, out, nullptr, 1);
}

// Round 9
// 282.917 us; speedup vs baseline: 1.2860x; 1.1846x over previous
//
#include <hip/hip_runtime.h>
#include <hip/hip_bf16.h>
#include <cstdint>
#include <cstddef>

typedef __attribute__((ext_vector_type(8))) short short8;   // 8 x bf16 (4 VGPRs)
typedef __attribute__((ext_vector_type(4))) float f32x4;    // MFMA accumulator

#define GLL(gp, lp) __builtin_amdgcn_global_load_lds(                         \
    (const __attribute__((address_space(1))) void*)(gp),                      \
    (__attribute__((address_space(3))) void*)(lp), 16, 0, 0)

static __device__ __forceinline__ unsigned short f2bf(float f) {
    union { float f; uint32_t u; } v; v.f = f;
    uint32_t r = v.u + 0x7FFF + ((v.u >> 16) & 1);   // round-to-nearest-even
    return (unsigned short)(r >> 16);
}

// ---------------------------------------------------------------------------
// fp32 -> bf16 elementwise (vectorized float4 -> 4x bf16)
// ---------------------------------------------------------------------------
__global__ void cvt_x_kernel(const float* __restrict__ src,
                             unsigned short* __restrict__ dst, int n4) {
    int i = blockIdx.x * blockDim.x + threadIdx.x;
    if (i < n4) {
        float4 v = *reinterpret_cast<const float4*>(src + (size_t)i * 4);
        unsigned short* d = dst + (size_t)i * 4;
        d[0] = f2bf(v.x); d[1] = f2bf(v.y); d[2] = f2bf(v.z); d[3] = f2bf(v.w);
    }
}

// ---------------------------------------------------------------------------
// ALL weight transposes fused in one launch: KxN fp32 -> NxK bf16.
// Flat 1D grid of 32x32 tiles; segments: Wq,Wk,Wv (->WqkvT), Wo, W1, W2.
// ---------------------------------------------------------------------------
__global__ void tr_all_kernel(
    const float* __restrict__ Wq, const float* __restrict__ Wk,
    const float* __restrict__ Wv, const float* __restrict__ Wo,
    const float* __restrict__ W1, const float* __restrict__ W2,
    unsigned short* __restrict__ WqkvT, unsigned short* __restrict__ WoT,
    unsigned short* __restrict__ W1T, unsigned short* __restrict__ W2T)
{
    __shared__ float tile[32][33];
    const int bid = blockIdx.x;
    const float* src; unsigned short* dst; int K, N, local;
    if (bid < 4096) {                     // Wq/Wk/Wv/Wo: 1024x1024, 1024 tiles each
        int seg = bid >> 10; local = bid & 1023; K = 1024; N = 1024;
        src = (seg == 0) ? Wq : (seg == 1) ? Wk : (seg == 2) ? Wv : Wo;
        dst = (seg < 3) ? WqkvT + (size_t)seg * 1024 * 1024 : WoT;
    } else if (bid < 8192) {              // W1: 1024x4096
        local = bid - 4096; K = 1024; N = 4096; src = W1; dst = W1T;
    } else {                              // W2: 4096x1024
        local = bid - 8192; K = 4096; N = 1024; src = W2; dst = W2T;
    }
    const int ntx = N >> 5;
    const int n0 = (local % ntx) * 32, k0 = (local / ntx) * 32;
    const int tx = threadIdx.x, ty = threadIdx.y;      // block (32, 8)
#pragma unroll
    for (int j = 0; j < 32; j += 8)
        tile[ty + j][tx] = src[(size_t)(k0 + ty + j) * N + n0 + tx];
    __syncthreads();
#pragma unroll
    for (int j = 0; j < 32; j += 8)
        dst[(size_t)(n0 + ty + j) * K + k0 + tx] = f2bf(tile[tx][ty + j]);
}

// ---------------------------------------------------------------------------
// 128x128 2-phase GEMM (R5-proven): BK=64, per K-step STAGE(next) first,
// ds_read + 32 MFMA on current, ONE vmcnt(0)+s_barrier. Split-K capable:
// grid.z = k-slices of size Kslice; ld = full K (row stride).
// EPI: 0 = QKV split (+bias, Q*0.125*log2e, V transposed),
//      4 = raw fp32 partial to out0 + z*M*N  (bias/resid applied later in LN)
// ---------------------------------------------------------------------------
template <int EPI>
__global__ __launch_bounds__(256) void gemm128_kernel(
    const unsigned short* __restrict__ A, const unsigned short* __restrict__ BT,
    int M, int N, int ld, int Kslice,
    const float* __restrict__ bias0, const float* __restrict__ bias1,
    const float* __restrict__ bias2,
    void* __restrict__ out0, void* __restrict__ out1, void* __restrict__ out2)
{
    __shared__ unsigned short Asm[2][128 * 64];
    __shared__ unsigned short Bsm[2][128 * 64];

    const int t = threadIdx.x;
    const int lane = t & 63, wv = t >> 6;
    const int wr = wv >> 1, wc = wv & 1;

    // T1: XCD-aware bijective swizzle within the z-slice (nwg % 8 == 0)
    const int gx = gridDim.x;
    const int nwg = gx * gridDim.y;
    const int id = blockIdx.y * gx + blockIdx.x;
    const int swz = (id & 7) * (nwg >> 3) + (id >> 3);
    const int rowBase = (swz / gx) * 128;
    const int colBase = (swz % gx) * 128;
    const int koff = blockIdx.z * Kslice;

    const int r0 = t >> 3, c0 = t & 7;
    const int cg = c0 ^ (r0 & 7);
    const unsigned short* gA = A + (size_t)(rowBase + r0) * ld + koff + cg * 8;
    const unsigned short* gB = BT + (size_t)(colBase + r0) * ld + koff + cg * 8;

    auto stage = [&](int buf, int kt) {
#pragma unroll
        for (int j = 0; j < 4; j++) {
            GLL(gA + (size_t)(32 * j) * ld + kt, &Asm[buf][t * 8 + 2048 * j]);
            GLL(gB + (size_t)(32 * j) * ld + kt, &Bsm[buf][t * 8 + 2048 * j]);
        }
    };

    int aoff[4][2], boff[4][2];
#pragma unroll
    for (int m = 0; m < 4; m++)
#pragma unroll
        for (int ks = 0; ks < 2; ks++) {
            int rl = wr * 64 + m * 16 + (lane & 15);
            aoff[m][ks] = rl * 64 + (((ks * 4 + (lane >> 4)) ^ (rl & 7)) << 3);
            int cl = wc * 64 + m * 16 + (lane & 15);
            boff[m][ks] = cl * 64 + (((ks * 4 + (lane >> 4)) ^ (cl & 7)) << 3);
        }

    f32x4 acc[4][4];
#pragma unroll
    for (int m = 0; m < 4; m++)
#pragma unroll
        for (int n = 0; n < 4; n++) acc[m][n] = (f32x4){0.f, 0.f, 0.f, 0.f};

    stage(0, 0);
    asm volatile("s_waitcnt vmcnt(0)" ::: "memory");
    __builtin_amdgcn_s_barrier();

    const int nt = Kslice >> 6;
    for (int tt = 0; tt < nt; ++tt) {
        const int cur = tt & 1;
        if (tt + 1 < nt) stage(cur ^ 1, (tt + 1) << 6);   // prefetch FIRST

        short8 b[4][2];
#pragma unroll
        for (int n = 0; n < 4; n++)
#pragma unroll
            for (int ks = 0; ks < 2; ks++)
                b[n][ks] = *(const short8*)&Bsm[cur][boff[n][ks]];
        __builtin_amdgcn_s_setprio(1);
#pragma unroll
        for (int m = 0; m < 4; m++) {
            short8 a0 = *(const short8*)&Asm[cur][aoff[m][0]];
            short8 a1 = *(const short8*)&Asm[cur][aoff[m][1]];
#pragma unroll
            for (int n = 0; n < 4; n++) {
                acc[m][n] = __builtin_amdgcn_mfma_f32_16x16x32_bf16(
                    a0, b[n][0], acc[m][n], 0, 0, 0);
                acc[m][n] = __builtin_amdgcn_mfma_f32_16x16x32_bf16(
                    a1, b[n][1], acc[m][n], 0, 0, 0);
            }
        }
        __builtin_amdgcn_s_setprio(0);

        asm volatile("s_waitcnt vmcnt(0)" ::: "memory");
        __builtin_amdgcn_sched_barrier(0);
        __builtin_amdgcn_s_barrier();
    }

#pragma unroll
    for (int m = 0; m < 4; m++) {
#pragma unroll
        for (int n = 0; n < 4; n++) {
            const int col = colBase + wc * 64 + n * 16 + (lane & 15);
#pragma unroll
            for (int i = 0; i < 4; i++) {
                const int row = rowBase + wr * 64 + m * 16 + (lane >> 4) * 4 + i;
                float v = acc[m][n][i];
                if (EPI == 0) {
                    const int bb = row >> 11, s = row & 2047;
                    if (col < 1024) {
                        float q = (v + bias0[col]) * 0.18033688011112042f;
                        int h = col >> 6, d = col & 63;
                        ((unsigned short*)out0)[((size_t)(bb * 16 + h) * 2048 + s) * 64 + d] = f2bf(q);
                    } else if (col < 2048) {
                        int cc = col - 1024;
                        float kv = v + bias1[cc];
                        int h = cc >> 6, d = cc & 63;
                        ((unsigned short*)out1)[((size_t)(bb * 16 + h) * 2048 + s) * 64 + d] = f2bf(kv);
                    } else {
                        int cc = col - 2048;
                        float vv = v + bias2[cc];
                        int h = cc >> 6, d = cc & 63;
                        ((unsigned short*)out2)[((size_t)(bb * 16 + h) * 64 + d) * 2048 + s] = f2bf(vv);
                    }
                } else {   // EPI == 4: raw fp32 partial
                    ((float*)out0)[(size_t)blockIdx.z * M * N + (size_t)row * N + col] = v;
                }
            }
        }
    }
}

// ---------------------------------------------------------------------------
// 256x256 2-phase GEMM (R5-proven): BK=64, 512 threads = 8 waves (2Mx4N).
// EPI: 2 = bf16 tanh-gelu(relu(+bias))
// ---------------------------------------------------------------------------
template <int EPI>
__global__ __launch_bounds__(512, 2) void gemm256_kernel(
    const unsigned short* __restrict__ A, const unsigned short* __restrict__ BT,
    int M, int N, int K,
    const float* __restrict__ bias0, void* __restrict__ out0)
{
    extern __shared__ unsigned short lds[];   // 65536 elems = 128 KiB

    const int t = threadIdx.x, lane = t & 63, w = t >> 6;
    const int wm = w >> 2, wn = w & 3;

    const int gx = gridDim.x;
    const int nwg = gx * gridDim.y;
    const int id = blockIdx.y * gx + blockIdx.x;
    const int swz = (id & 7) * (nwg >> 3) + (id >> 3);
    const int rowBase = (swz / gx) * 256;
    const int colBase = (swz % gx) * 256;

    const int r0 = t >> 3, c0 = t & 7;
    const int cg = c0 ^ (r0 & 7);
    const unsigned short* gA = A + (size_t)(rowBase + r0) * K + cg * 8;
    const unsigned short* gB = BT + (size_t)(colBase + r0) * K + cg * 8;

    auto stage = [&](int buf, int kt) {
#pragma unroll
        for (int j = 0; j < 4; j++) {
            GLL(gA + (size_t)(64 * j) * K + kt, &lds[buf * 16384 + t * 8 + 4096 * j]);
            GLL(gB + (size_t)(64 * j) * K + kt, &lds[32768 + buf * 16384 + t * 8 + 4096 * j]);
        }
    };

    int aoff[8][2], boff[4][2];
#pragma unroll
    for (int mf = 0; mf < 8; mf++)
#pragma unroll
        for (int ks = 0; ks < 2; ks++) {
            int rl = wm * 128 + mf * 16 + (lane & 15);
            aoff[mf][ks] = rl * 64 + (((ks * 4 + (lane >> 4)) ^ (rl & 7)) << 3);
        }
#pragma unroll
    for (int nf = 0; nf < 4; nf++)
#pragma unroll
        for (int ks = 0; ks < 2; ks++) {
            int cl = wn * 64 + nf * 16 + (lane & 15);
            boff[nf][ks] = cl * 64 + (((ks * 4 + (lane >> 4)) ^ (cl & 7)) << 3);
        }

    f32x4 acc[8][4];
#pragma unroll
    for (int mf = 0; mf < 8; mf++)
#pragma unroll
        for (int nf = 0; nf < 4; nf++) acc[mf][nf] = (f32x4){0.f, 0.f, 0.f, 0.f};

    stage(0, 0);
    asm volatile("s_waitcnt vmcnt(0)" ::: "memory");
    __builtin_amdgcn_s_barrier();

    const int nt = K >> 6;
    for (int tt = 0; tt < nt; ++tt) {
        const int cur = tt & 1;
        const int ab = cur * 16384, bbase = 32768 + cur * 16384;
        if (tt + 1 < nt) stage(cur ^ 1, (tt + 1) << 6);

        short8 b[4][2];
#pragma unroll
        for (int nf = 0; nf < 4; nf++)
#pragma unroll
            for (int ks = 0; ks < 2; ks++)
                b[nf][ks] = *(const short8*)&lds[bbase + boff[nf][ks]];
        __builtin_amdgcn_s_setprio(1);
#pragma unroll
        for (int mf = 0; mf < 8; mf++) {
            short8 a0 = *(const short8*)&lds[ab + aoff[mf][0]];
            short8 a1 = *(const short8*)&lds[ab + aoff[mf][1]];
#pragma unroll
            for (int nf = 0; nf < 4; nf++) {
                acc[mf][nf] = __builtin_amdgcn_mfma_f32_16x16x32_bf16(
                    a0, b[nf][0], acc[mf][nf], 0, 0, 0);
                acc[mf][nf] = __builtin_amdgcn_mfma_f32_16x16x32_bf16(
                    a1, b[nf][1], acc[mf][nf], 0, 0, 0);
            }
        }
        __builtin_amdgcn_s_setprio(0);

        asm volatile("s_waitcnt vmcnt(0)" ::: "memory");
        __builtin_amdgcn_sched_barrier(0);
        __builtin_amdgcn_s_barrier();
    }

#pragma unroll
    for (int mf = 0; mf < 8; mf++) {
#pragma unroll
        for (int nf = 0; nf < 4; nf++) {
            const int col = colBase + wn * 64 + nf * 16 + (lane & 15);
#pragma unroll
            for (int i = 0; i < 4; i++) {
                const int row = rowBase + wm * 128 + mf * 16 + (lane >> 4) * 4 + i;
                float z = acc[mf][nf][i] + bias0[col];
                if (z > 0.f) {
                    float u = 0.7978845608f * (z + 0.044715f * z * z * z);
                    float e = __builtin_amdgcn_exp2f(u * 2.8853900817779268f);
                    z = z * (1.f - 1.f / (e + 1.f));
                } else z = 0.f;
                ((unsigned short*)out0)[(size_t)row * N + col] = f2bf(z);
            }
        }
    }
}

// ---------------------------------------------------------------------------
// Flash attention, 2-phase double-buffered K/V staging (unchanged).
// ---------------------------------------------------------------------------
__global__ __launch_bounds__(256, 4) void flash_attn_kernel(
    const unsigned short* __restrict__ Qb, const unsigned short* __restrict__ Kb,
    const unsigned short* __restrict__ VT, unsigned short* __restrict__ ctxb)
{
    __shared__ unsigned short Ksm[2][64 * 64];
    __shared__ unsigned short Vsm[2][64 * 64];
    __shared__ unsigned short Psm[4][16 * 64];

    const int bh = blockIdx.y;
    const int q0 = blockIdx.x * 64;
    const int t = threadIdx.x, lane = t & 63, wv = t >> 6;

    const unsigned short* Qg = Qb + (size_t)bh * 2048 * 64;
    const unsigned short* Kg = Kb + (size_t)bh * 2048 * 64;
    const unsigned short* Vg = VT + (size_t)bh * 64 * 2048;

    short8 qf[2];
    {
        int r = q0 + wv * 16 + (lane & 15);
        qf[0] = *(const short8*)&Qg[(size_t)r * 64 + ((lane >> 4) << 3)];
        qf[1] = *(const short8*)&Qg[(size_t)r * 64 + 32 + ((lane >> 4) << 3)];
    }

    f32x4 o[4];
#pragma unroll
    for (int n = 0; n < 4; n++) o[n] = (f32x4){0.f, 0.f, 0.f, 0.f};
    float mrun[4], lpart[4];
#pragma unroll
    for (int i = 0; i < 4; i++) { mrun[i] = -3.0e38f; lpart[i] = 0.f; }

    const int r0 = t >> 3, sl = t & 7;
    const int cg0 = sl ^ (r0 & 7);
    const int r1 = (256 + t) >> 3;
    const int cg1 = sl ^ (r1 & 7);

    auto stageKV = [&](int buf, int kt) {
        GLL(&Kg[(size_t)(kt + r0) * 64 + cg0 * 8], &Ksm[buf][t * 8]);
        GLL(&Kg[(size_t)(kt + r1) * 64 + cg1 * 8], &Ksm[buf][(256 + t) * 8]);
        GLL(&Vg[(size_t)r0 * 2048 + kt + cg0 * 8], &Vsm[buf][t * 8]);
        GLL(&Vg[(size_t)r1 * 2048 + kt + cg1 * 8], &Vsm[buf][(256 + t) * 8]);
    };

    unsigned short* P = &Psm[wv][0];

    int pwaddr[4][4];
#pragma unroll
    for (int n = 0; n < 4; n++)
#pragma unroll
        for (int i = 0; i < 4; i++) {
            int rl = (lane >> 4) * 4 + i;
            int col = n * 16 + (lane & 15);
            pwaddr[n][i] = rl * 64 + ((((col >> 3) ^ (rl & 7)) << 3) | (col & 7));
        }

    stageKV(0, 0);
    asm volatile("s_waitcnt vmcnt(0)" ::: "memory");
    __builtin_amdgcn_s_barrier();

    for (int tt = 0; tt < 32; ++tt) {
        const int cur = tt & 1;
        if (tt + 1 < 32) stageKV(cur ^ 1, (tt + 1) << 6);   // prefetch FIRST

        f32x4 s[4];
        __builtin_amdgcn_s_setprio(1);
#pragma unroll
        for (int n = 0; n < 4; n++) {
            s[n] = (f32x4){0.f, 0.f, 0.f, 0.f};
            int rl = n * 16 + (lane & 15);
#pragma unroll
            for (int kb = 0; kb < 2; kb++) {
                int slot = ((kb << 2) + (lane >> 4)) ^ (rl & 7);
                short8 kf = *(const short8*)&Ksm[cur][rl * 64 + slot * 8];
                s[n] = __builtin_amdgcn_mfma_f32_16x16x32_bf16(qf[kb], kf, s[n], 0, 0, 0);
            }
        }
        __builtin_amdgcn_s_setprio(0);

        float mx[4];
#pragma unroll
        for (int i = 0; i < 4; i++) {
            float m0 = fmaxf(fmaxf(s[0][i], s[1][i]), fmaxf(s[2][i], s[3][i]));
#pragma unroll
            for (int off = 1; off < 16; off <<= 1)
                m0 = fmaxf(m0, __shfl_xor(m0, off));
            mx[i] = m0;
        }
        bool ok = (mx[0] <= mrun[0] + 8.f) && (mx[1] <= mrun[1] + 8.f) &&
                  (mx[2] <= mrun[2] + 8.f) && (mx[3] <= mrun[3] + 8.f);
        if (!__all(ok)) {
#pragma unroll
            for (int i = 0; i < 4; i++) {
                float mnew = fmaxf(mrun[i], mx[i]);
                float sc = __builtin_amdgcn_exp2f(mrun[i] - mnew);
                mrun[i] = mnew;
                lpart[i] *= sc;
#pragma unroll
                for (int n = 0; n < 4; n++) o[n][i] *= sc;
            }
        }
#pragma unroll
        for (int n = 0; n < 4; n++)
#pragma unroll
            for (int i = 0; i < 4; i++) {
                float p = __builtin_amdgcn_exp2f(s[n][i] - mrun[i]);
                union { float f; uint32_t u; } pv; pv.f = p;
                P[pwaddr[n][i]] = (unsigned short)(pv.u >> 16);
                pv.u &= 0xffff0000u;
                lpart[i] += pv.f;
            }

        short8 pf[2];
        {
            int rl = lane & 15;
#pragma unroll
            for (int kb = 0; kb < 2; kb++) {
                int slot = ((kb << 2) + (lane >> 4)) ^ (rl & 7);
                pf[kb] = *(const short8*)&P[rl * 64 + slot * 8];
            }
        }
        __builtin_amdgcn_s_setprio(1);
#pragma unroll
        for (int n = 0; n < 4; n++) {
            int d = n * 16 + (lane & 15);
#pragma unroll
            for (int kb = 0; kb < 2; kb++) {
                int slot = ((kb << 2) + (lane >> 4)) ^ (d & 7);
                short8 vf = *(const short8*)&Vsm[cur][d * 64 + slot * 8];
                o[n] = __builtin_amdgcn_mfma_f32_16x16x32_bf16(pf[kb], vf, o[n], 0, 0, 0);
            }
        }
        __builtin_amdgcn_s_setprio(0);

        asm volatile("s_waitcnt vmcnt(0)" ::: "memory");
        __builtin_amdgcn_sched_barrier(0);
        __builtin_amdgcn_s_barrier();
    }

    float linv[4];
#pragma unroll
    for (int i = 0; i < 4; i++) {
        float li = lpart[i];
#pragma unroll
        for (int off = 1; off < 16; off <<= 1)
            li += __shfl_xor(li, off);
        linv[i] = 1.f / li;
    }
    const int bb = bh >> 4, h = bh & 15;
#pragma unroll
    for (int n = 0; n < 4; n++)
#pragma unroll
        for (int i = 0; i < 4; i++) {
            int srow = q0 + wv * 16 + (lane >> 4) * 4 + i;
            int d = n * 16 + (lane & 15);
            ctxb[((size_t)(bb * 2048 + srow)) * 1024 + h * 64 + d] =
                f2bf(o[n][i] * linv[i]);
        }
}

// ---------------------------------------------------------------------------
// LayerNorm over D=1024 with fused split-K reduce:
// x = in0 + (in1?) + bias + (resid?); outputs fp32 (+ optional bf16 copy).
// Null-pointer branches are kernel-uniform (no divergence).
// ---------------------------------------------------------------------------
__global__ __launch_bounds__(256) void ln_kernel(
    const float* __restrict__ in0, const float* __restrict__ in1,
    const float* __restrict__ resid, const float* __restrict__ bias,
    const float* __restrict__ g, const float* __restrict__ bta,
    float* __restrict__ outf, unsigned short* __restrict__ outb)
{
    const int row = blockIdx.x;
    const int t = threadIdx.x, lane = t & 63, wv = t >> 6;
    const size_t base = (size_t)row * 1024 + t * 4;

    float4 xv = *reinterpret_cast<const float4*>(in0 + base);
    if (in1) {
        float4 v1 = *reinterpret_cast<const float4*>(in1 + base);
        xv.x += v1.x; xv.y += v1.y; xv.z += v1.z; xv.w += v1.w;
    }
    if (resid) {
        float4 rv = *reinterpret_cast<const float4*>(resid + base);
        xv.x += rv.x; xv.y += rv.y; xv.z += rv.z; xv.w += rv.w;
    }
    {
        float4 bv = *reinterpret_cast<const float4*>(bias + t * 4);
        xv.x += bv.x; xv.y += bv.y; xv.z += bv.z; xv.w += bv.w;
    }

    float s = xv.x + xv.y + xv.z + xv.w;
    float ss = xv.x * xv.x + xv.y * xv.y + xv.z * xv.z + xv.w * xv.w;
#pragma unroll
    for (int off = 1; off < 64; off <<= 1) {
        s += __shfl_xor(s, off);
        ss += __shfl_xor(ss, off);
    }
    __shared__ float red[8];
    if (lane == 0) { red[wv] = s; red[4 + wv] = ss; }
    __syncthreads();
    s = red[0] + red[1] + red[2] + red[3];
    ss = red[4] + red[5] + red[6] + red[7];
    const float mu = s * (1.f / 1024.f);
    const float var = ss * (1.f / 1024.f) - mu * mu;
    const float inv = rsqrtf(var + 1e-12f);

    float4 gv = *reinterpret_cast<const float4*>(g + t * 4);
    float4 bv = *reinterpret_cast<const float4*>(bta + t * 4);
    float o0 = (xv.x - mu) * inv * gv.x + bv.x;
    float o1 = (xv.y - mu) * inv * gv.y + bv.y;
    float o2 = (xv.z - mu) * inv * gv.z + bv.z;
    float o3 = (xv.w - mu) * inv * gv.w + bv.w;

    *reinterpret_cast<float4*>(outf + base) = (float4){o0, o1, o2, o3};
    if (outb) {
        unsigned short* ob = outb + base;
        ob[0] = f2bf(o0); ob[1] = f2bf(o1); ob[2] = f2bf(o2); ob[3] = f2bf(o3);
    }
}

// ---------------------------------------------------------------------------
extern "C" void kernel_launch(void* const* d_in, const int* in_sizes, int n_in,
                              void* d_out, int out_size, void* d_ws, size_t ws_size,
                              hipStream_t stream) {
    const float* x     = (const float*)d_in[0];
    const float* Wq    = (const float*)d_in[1];
    const float* bq    = (const float*)d_in[2];
    const float* Wk    = (const float*)d_in[3];
    const float* bk    = (const float*)d_in[4];
    const float* Wv    = (const float*)d_in[5];
    const float* bv    = (const float*)d_in[6];
    const float* Wo    = (const float*)d_in[7];
    const float* bo    = (const float*)d_in[8];
    const float* ln1_g = (const float*)d_in[9];
    const float* ln1_b = (const float*)d_in[10];
    const float* W1    = (const float*)d_in[11];
    const float* b1    = (const float*)d_in[12];
    const float* W2    = (const float*)d_in[13];
    const float* b2    = (const float*)d_in[14];
    const float* ln2_g = (const float*)d_in[15];
    const float* ln2_b = (const float*)d_in[16];
    float* out = (float*)d_out;

    const int B = 2, S = 2048, D = 1024, H = 16, F = 4096;
    const int M = B * S;                    // 4096 tokens

    char* w = (char*)d_ws;
    size_t off = 0;
    auto alloc = [&](size_t bytes) {
        size_t o = off; off += (bytes + 255) & ~(size_t)255; return o;
    };
    unsigned short* xb      = (unsigned short*)(w + alloc((size_t)M * D * 2));   // also ctxb
    unsigned short* WqkvT   = (unsigned short*)(w + alloc((size_t)3 * D * D * 2));
    unsigned short* WoT     = (unsigned short*)(w + alloc((size_t)D * D * 2));
    unsigned short* W1T     = (unsigned short*)(w + alloc((size_t)D * F * 2));
    unsigned short* W2T     = (unsigned short*)(w + alloc((size_t)F * D * 2));
    unsigned short* Qbuf    = (unsigned short*)(w + alloc((size_t)M * D * 2));
    unsigned short* Kbuf    = (unsigned short*)(w + alloc((size_t)M * D * 2));
    unsigned short* VTbuf   = (unsigned short*)(w + alloc((size_t)M * D * 2));
    float*          z0      = (float*)(w + alloc((size_t)M * D * 4));            // partial 0
    float*          z1      = (float*)(w + alloc((size_t)M * D * 4));            // partial 1
    float*          attnlnf = (float*)(w + alloc((size_t)M * D * 4));
    unsigned short* attnlnb = (unsigned short*)(w + alloc((size_t)M * D * 2));
    unsigned short* hbuf    = (unsigned short*)(w + alloc((size_t)M * F * 2));
    unsigned short* ctxb    = xb;   // reuse (xb consumed by GEMM1 before attn)

    hipFuncSetAttribute((const void*)gemm256_kernel<2>,
                        hipFuncAttributeMaxDynamicSharedMemorySize, 131072);

    // 1) input cvt + all weight transposes (one launch each)
    cvt_x_kernel<<<(M * D / 4 + 255) / 256, 256, 0, stream>>>(x, xb, M * D / 4);
    tr_all_kernel<<<12288, dim3(32, 8), 0, stream>>>(
        Wq, Wk, Wv, Wo, W1, W2, WqkvT, WoT, W1T, W2T);

    // 2) fused QKV projection (128-tile 2-phase, full K)
    gemm128_kernel<0><<<dim3(3 * D / 128, M / 128, 1), 256, 0, stream>>>(
        xb, WqkvT, M, 3 * D, D, D, bq, bk, bv, Qbuf, Kbuf, VTbuf);

    // 3) flash attention -> ctx bf16 (token-major)
    flash_attn_kernel<<<dim3(S / 64, B * H), 256, 0, stream>>>(
        Qbuf, Kbuf, VTbuf, ctxb);

    // 4) output projection, split-K=2 -> fp32 partials z0,z1
    gemm128_kernel<4><<<dim3(D / 128, M / 128, 2), 256, 0, stream>>>(
        ctxb, WoT, M, D, D, D / 2, nullptr, nullptr, nullptr, z0, nullptr, nullptr);

    // 5) LN1 (reduces z0+z1+bo) -> fp32 residual + bf16 GEMM input
    ln_kernel<<<M, 256, 0, stream>>>(z0, z1, nullptr, bo, ln1_g, ln1_b,
                                     attnlnf, attnlnb);

    // 6) FFN up + relu + tanh-gelu -> bf16 (256-tile 2-phase)
    gemm256_kernel<2><<<dim3(F / 256, M / 256), 512, 131072, stream>>>(
        attnlnb, W1T, M, F, D, b1, hbuf);

    // 7) FFN down, split-K=2 (K=4096 -> 2x2048) -> fp32 partials z0,z1
    gemm128_kernel<4><<<dim3(D / 128, M / 128, 2), 256, 0, stream>>>(
        hbuf, W2T, M, D, F, F / 2, nullptr, nullptr, nullptr, z0, nullptr, nullptr);

    // 8) LN2 (reduces z0+z1+b2+resid) -> final output fp32
    ln_kernel<<<M, 256, 0, stream>>>(z0, z1, attnlnf, b2, ln2_g, ln2_b,
                                     out, nullptr);
}